// Round 4
// baseline (677.878 us; speedup 1.0000x reference)
//
#include <hip/hip_runtime.h>

#define B_ 16
#define L_ 128
#define ML_ 2048
#define E_ 300
#define H_ 128
#define G_ 512
#define EPSV 1e-8f

typedef const float* fp;

__device__ __forceinline__ float sigm(float x) { return 1.f / (1.f + __expf(-x)); }
__device__ __forceinline__ float tanh_f(float x) {
  float e = __expf(-2.f * fabsf(x));
  float r = (1.f - e) / (1.f + e);
  return copysignf(r, x);
}
__device__ __forceinline__ float ddiv(float n, float d) {
  return n / (d > EPSV ? d : EPSV);
}

// ---------------- context input projection: xg[z][m][g] = emb[text] @ W^T + bih + bhh
// grid (32, 8, 4) block 256. z = inp*2 + dir.
__global__ __launch_bounds__(256) void k_proj(
    fp __restrict__ emb,
    const int* __restrict__ ta, const int* __restrict__ tb,
    fp Wf, fp Wb, fp bihf, fp bhhf, fp bihb, fp bhhb,
    float* __restrict__ xg)
{
  const int z = blockIdx.z;
  const int* txt = (z >> 1) ? tb : ta;
  fp W = (z & 1) ? Wb : Wf;
  fp bih = (z & 1) ? bihb : bihf;
  fp bhh = (z & 1) ? bhhb : bhhf;
  float* out = xg + (size_t)z * ML_ * G_;
  const int m0 = blockIdx.x * 64, n0 = blockIdx.y * 64;
  __shared__ float As[12][64];
  __shared__ float Bs[12][64];
  __shared__ int rowidx[64];
  const int tid = threadIdx.x;
  if (tid < 64) rowidx[tid] = txt[m0 + tid];
  __syncthreads();
  const int tm = tid >> 4, tn = tid & 15;
  float acc[4][4] = {};
  for (int k0 = 0; k0 < 300; k0 += 12) {
    for (int i = tid; i < 768; i += 256) {
      int m = i / 12, k = i - m * 12;
      As[k][m] = emb[(size_t)rowidx[m] * 300 + k0 + k];
    }
    for (int i = tid; i < 768; i += 256) {
      int n = i / 12, k = i - n * 12;
      Bs[k][n] = W[(size_t)(n0 + n) * 300 + k0 + k];
    }
    __syncthreads();
    #pragma unroll
    for (int k = 0; k < 12; ++k) {
      float4 a = *(const float4*)&As[k][tm * 4];
      float4 bv = *(const float4*)&Bs[k][tn * 4];
      float aa[4] = {a.x, a.y, a.z, a.w};
      #pragma unroll
      for (int i = 0; i < 4; ++i) {
        acc[i][0] = fmaf(aa[i], bv.x, acc[i][0]);
        acc[i][1] = fmaf(aa[i], bv.y, acc[i][1]);
        acc[i][2] = fmaf(aa[i], bv.z, acc[i][2]);
        acc[i][3] = fmaf(aa[i], bv.w, acc[i][3]);
      }
    }
    __syncthreads();
  }
  float biasv[4];
  #pragma unroll
  for (int j = 0; j < 4; ++j)
    biasv[j] = bih[n0 + tn * 4 + j] + bhh[n0 + tn * 4 + j];
  #pragma unroll
  for (int i = 0; i < 4; ++i) {
    float* row = out + (size_t)(m0 + tm * 4 + i) * G_ + n0 + tn * 4;
    #pragma unroll
    for (int j = 0; j < 4; ++j) row[j] = acc[i][j] + biasv[j];
  }
}

// ---------------- LSTM scan. grid (16, 4) block 256. One WG per (z, b) scan.
// Round-3 redesign: 2 gate-rows per thread (4 waves), so the per-step LDS
// broadcast of h costs 128 ds_read_b128 wave-insts instead of 256 (round-3
// profile: LDS-issue bound, VALUBusy 13%). Gate exchange via shfl_xor(32)
// (lanes 0-31 own (i,g), lanes 32-63 own (f,o) for the same j) removes the
// gb[] LDS round-trip; hs double-buffer leaves ONE barrier per step.
__global__ __launch_bounds__(256, 1) void k_lstm(
    fp __restrict__ xg, fp Whhf, fp Whhb, float* __restrict__ out)
{
  const int b = blockIdx.x, z = blockIdx.y, dir = z & 1;
  fp Whh = dir ? Whhb : Whhf;
  fp __restrict__ xgz = xg + ((size_t)z * ML_ + (size_t)b * L_) * G_;
  float* __restrict__ outz = out + ((size_t)z * ML_ + (size_t)b * L_) * H_;
  const int tid = threadIdx.x;
  const int wv = tid >> 6, lane = tid & 63;
  const int half = lane >> 5;            // 0: owns (i,g); 1: owns (f,o)
  const int j = wv * 32 + (lane & 31);   // hidden index
  const int g0 = half ? (128 + j) : j;          // f_j : i_j
  const int g1 = half ? (384 + j) : (256 + j);  // o_j : g_j
  // two weight rows resident in VGPRs (2*128 f32 = 256 VGPR; 1 wave/SIMD)
  float4 wA[32], wB[32];
  {
    const float4* pA = (const float4*)(Whh + (size_t)g0 * H_);
    const float4* pB = (const float4*)(Whh + (size_t)g1 * H_);
    #pragma unroll
    for (int q = 0; q < 32; ++q) wA[q] = pA[q];
    #pragma unroll
    for (int q = 0; q < 32; ++q) wB[q] = pB[q];
  }
  __shared__ float hs[2][128];
  if (tid < 128) hs[0][tid] = 0.f;
  float c = 0.f;                         // replicated in both partner lanes
  float xvA = xgz[(size_t)(dir ? (L_ - 1) : 0) * G_ + g0];
  float xvB = xgz[(size_t)(dir ? (L_ - 1) : 0) * G_ + g1];
  __syncthreads();
  int cur = 0;
  for (int t = 0; t < L_; ++t) {
    const int pos = dir ? (L_ - 1 - t) : t;
    // prefetch next step's x (consumed next iteration)
    const int tn = (t + 1 < L_) ? (t + 1) : t;
    const int posn = dir ? (L_ - 1 - tn) : tn;
    float xvA_n = xgz[(size_t)posn * G_ + g0];
    float xvB_n = xgz[(size_t)posn * G_ + g1];
    // two dots over hs[cur] sharing one broadcast read stream
    float a0=0.f,a1=0.f,a2=0.f,a3=0.f;
    float b0=0.f,b1=0.f,b2=0.f,b3=0.f;
    const float4* h4 = (const float4*)hs[cur];
    #pragma unroll
    for (int q = 0; q < 32; ++q) {
      float4 hv = h4[q];
      float4 va = wA[q], vb = wB[q];
      a0 = fmaf(va.x, hv.x, a0);
      a1 = fmaf(va.y, hv.y, a1);
      a2 = fmaf(va.z, hv.z, a2);
      a3 = fmaf(va.w, hv.w, a3);
      b0 = fmaf(vb.x, hv.x, b0);
      b1 = fmaf(vb.y, hv.y, b1);
      b2 = fmaf(vb.z, hv.z, b2);
      b3 = fmaf(vb.w, hv.w, b3);
    }
    float accA = xvA + ((a0 + a1) + (a2 + a3));
    float accB = xvB + ((b0 + b1) + (b2 + b3));
    // half0: sA=sigm(i), sB=tanh(g) ; half1: sA=sigm(f), sB=sigm(o)
    float sA = sigm(accA);
    float sB = half ? sigm(accB) : tanh_f(accB);
    float pA = __shfl_xor(sA, 32, 64);   // half0 gets f ; half1 gets i
    float pB = __shfl_xor(sB, 32, 64);   // half0 gets o ; half1 gets g
    float iv = half ? pA : sA;
    float fv = half ? sA : pA;
    float gv = half ? pB : sB;
    float ov = half ? sB : pB;
    c = fmaf(fv, c, iv * gv);
    float hn = ov * tanh_f(c);
    const int nxt = cur ^ 1;
    if (half == 0) {
      hs[nxt][j] = hn;
      outz[(size_t)pos * H_ + j] = hn;
    }
    asm volatile("s_waitcnt lgkmcnt(0)" ::: "memory");
    __builtin_amdgcn_s_barrier();
    cur = nxt; xvA = xvA_n; xvB = xvB_n;
  }
}

// ---------------- attention + pairwise rows. grid (16, 2, 4) block 256.
__global__ __launch_bounds__(256) void k_att(
    fp __restrict__ con, fp w3, fp w4,
    float* __restrict__ att, float* __restrict__ ameanh, float* __restrict__ amaxh,
    float* __restrict__ pcpart, float* __restrict__ mv)
{
  const int b = blockIdx.x, dir = blockIdx.y, lt = blockIdx.z;
  const int l0 = lt * 32;
  fp __restrict__ cp = con + ((size_t)dir * B_ + b) * L_ * H_;
  fp __restrict__ ch = con + ((size_t)(2 + dir) * B_ + b) * L_ * H_;
  fp w = dir ? w4 : w3;
  float* __restrict__ attg = att + ((size_t)dir * B_ + b) * L_ * L_;
  __shared__ float cps[32][132];
  __shared__ float chs[32][132];
  __shared__ float w2s[4][128];
  __shared__ float attb[32][33];
  __shared__ float pcb[4][32][33];
  __shared__ float n0l[32], nql[4][32], n0m[32], nqm[4][32], asum_s[32];
  const int tid = threadIdx.x;
  for (int i = tid; i < 512; i += 256) {
    float wv = w[i];
    w2s[i >> 7][i & 127] = wv * wv;
  }
  for (int i = tid; i < 4096; i += 256)
    cps[i >> 7][i & 127] = cp[(size_t)(l0 + (i >> 7)) * H_ + (i & 127)];
  __syncthreads();
  for (int d = tid; d < 160; d += 256) {
    int l = d / 5, q = d - l * 5;
    const float4* vr = (const float4*)&cps[l][0];
    float s = 0.f;
    if (q == 0) {
      #pragma unroll 8
      for (int h4 = 0; h4 < 32; ++h4) {
        float4 v = vr[h4];
        s += v.x*v.x + v.y*v.y + v.z*v.z + v.w*v.w;
      }
      n0l[l] = sqrtf(s);
    } else {
      const float4* wr = (const float4*)&w2s[q - 1][0];
      #pragma unroll 8
      for (int h4 = 0; h4 < 32; ++h4) {
        float4 v = vr[h4]; float4 ww = wr[h4];
        s += v.x*v.x*ww.x + v.y*v.y*ww.y + v.z*v.z*ww.z + v.w*v.w*ww.w;
      }
      nql[q - 1][l] = sqrtf(s);
    }
  }
  const int tl = tid >> 3, t8 = tid & 7;
  float amean_acc[16], amax_acc[16];
  #pragma unroll
  for (int i = 0; i < 16; ++i) { amean_acc[i] = 0.f; amax_acc[i] = -3.4e38f; }
  float asum_reg = 0.f;
  float pmax_reg = -3.4e38f;
  for (int mc = 0; mc < 4; ++mc) {
    __syncthreads();
    for (int i = tid; i < 4096; i += 256)
      chs[i >> 7][i & 127] = ch[(size_t)(mc * 32 + (i >> 7)) * H_ + (i & 127)];
    __syncthreads();
    for (int d = tid; d < 160; d += 256) {
      int m = d / 5, q = d - m * 5;
      const float4* vr = (const float4*)&chs[m][0];
      float s = 0.f;
      if (q == 0) {
        #pragma unroll 8
        for (int h4 = 0; h4 < 32; ++h4) {
          float4 v = vr[h4];
          s += v.x*v.x + v.y*v.y + v.z*v.z + v.w*v.w;
        }
        n0m[m] = sqrtf(s);
      } else {
        const float4* wr = (const float4*)&w2s[q - 1][0];
        #pragma unroll 8
        for (int h4 = 0; h4 < 32; ++h4) {
          float4 v = vr[h4]; float4 ww = wr[h4];
          s += v.x*v.x*ww.x + v.y*v.y*ww.y + v.z*v.z*ww.z + v.w*v.w*ww.w;
        }
        nqm[q - 1][m] = sqrtf(s);
      }
    }
    __syncthreads();
    // phase A: gram rows for {1, w0..w3} weightings
    float a0[4], ap0[4], ap1[4], ap2[4], ap3[4];
    #pragma unroll
    for (int mm = 0; mm < 4; ++mm) { a0[mm]=0.f; ap0[mm]=0.f; ap1[mm]=0.f; ap2[mm]=0.f; ap3[mm]=0.f; }
    #pragma unroll 4
    for (int h4 = 0; h4 < 32; ++h4) {
      const float4 av = *(const float4*)&cps[tl][h4 * 4];
      const float4 q0 = *(const float4*)&w2s[0][h4 * 4];
      const float4 q1 = *(const float4*)&w2s[1][h4 * 4];
      const float4 q2 = *(const float4*)&w2s[2][h4 * 4];
      const float4 q3 = *(const float4*)&w2s[3][h4 * 4];
      #pragma unroll
      for (int mm = 0; mm < 4; ++mm) {
        const float4 cv = *(const float4*)&chs[t8 * 4 + mm][h4 * 4];
        float px = av.x * cv.x, py = av.y * cv.y, pz = av.z * cv.z, pw = av.w * cv.w;
        a0[mm] += (px + py) + (pz + pw);
        ap0[mm] += px * q0.x + py * q0.y + pz * q0.z + pw * q0.w;
        ap1[mm] += px * q1.x + py * q1.y + pz * q1.z + pw * q1.w;
        ap2[mm] += px * q2.x + py * q2.y + pz * q2.z + pw * q2.w;
        ap3[mm] += px * q3.x + py * q3.y + pz * q3.z + pw * q3.w;
      }
    }
    #pragma unroll
    for (int mm = 0; mm < 4; ++mm) {
      const int m = t8 * 4 + mm;
      float attv = ddiv(a0[mm], n0l[tl] * n0m[m]);
      attb[tl][m] = attv;
      attg[(size_t)(l0 + tl) * L_ + mc * 32 + m] = attv;
      pcb[0][tl][m] = ddiv(ap0[mm], nql[0][tl] * nqm[0][m]);
      pcb[1][tl][m] = ddiv(ap1[mm], nql[1][tl] * nqm[1][m]);
      pcb[2][tl][m] = ddiv(ap2[mm], nql[2][tl] * nqm[2][m]);
      pcb[3][tl][m] = ddiv(ap3[mm], nql[3][tl] * nqm[3][m]);
    }
    __syncthreads();
    // phase B: row reductions over this m-chunk
    for (int mq = 0; mq < 32; ++mq) {
      float avv = attb[tl][mq];
      const float4* cr = (const float4*)&chs[mq][t8 * 16];
      #pragma unroll
      for (int i = 0; i < 4; ++i) {
        float4 cv = cr[i];
        float t0 = avv * cv.x, t1 = avv * cv.y, t2 = avv * cv.z, t3 = avv * cv.w;
        amean_acc[4*i+0] += t0; amax_acc[4*i+0] = fmaxf(amax_acc[4*i+0], t0);
        amean_acc[4*i+1] += t1; amax_acc[4*i+1] = fmaxf(amax_acc[4*i+1], t1);
        amean_acc[4*i+2] += t2; amax_acc[4*i+2] = fmaxf(amax_acc[4*i+2], t2);
        amean_acc[4*i+3] += t3; amax_acc[4*i+3] = fmaxf(amax_acc[4*i+3], t3);
      }
    }
    if (tid < 32) {
      float s = 0.f;
      for (int mq = 0; mq < 32; ++mq) s += attb[tid][mq];
      asum_reg += s;
    }
    if (tid < 128) {
      const int p = tid >> 5, q = tid & 31;
      float mx = pmax_reg;
      for (int mq = 0; mq < 32; ++mq) mx = fmaxf(mx, pcb[p][q][mq]);
      pmax_reg = mx;
      float mx2 = -3.4e38f;
      for (int lq = 0; lq < 32; ++lq) mx2 = fmaxf(mx2, pcb[p][lq][q]);
      pcpart[((((size_t)dir * B_ + b) * 4 + lt) * 4 + p) * L_ + mc * 32 + q] = mx2;
    }
    __syncthreads();
  }
  if (tid < 32) asum_s[tid] = asum_reg;
  __syncthreads();
  {
    float den = asum_s[tl]; den = (den > EPSV) ? den : EPSV;
    const size_t base = (((size_t)dir * B_ + b) * L_ + l0 + tl) * H_ + t8 * 16;
    #pragma unroll
    for (int i = 0; i < 16; ++i) {
      ameanh[base + i] = amean_acc[i] / den;
      amaxh[base + i] = amax_acc[i];
    }
  }
  if (tid < 128) {
    const int p = tid >> 5, lq = tid & 31;
    mv[(size_t)(b * L_ + l0 + lq) * 32 + (dir ? 20 : 4) + p] = pmax_reg;
  }
}

// ---------------- column reductions. grid (16, 2, 4) block 256.
__global__ __launch_bounds__(256) void k_col(
    fp __restrict__ con, fp __restrict__ att,
    fp __restrict__ pcpart,
    float* __restrict__ ameanp, float* __restrict__ amaxp, float* __restrict__ mv)
{
  const int b = blockIdx.x, dir = blockIdx.y, mt = blockIdx.z;
  const int m0 = mt * 32;
  fp __restrict__ cp = con + ((size_t)dir * B_ + b) * L_ * H_;
  fp __restrict__ attg = att + ((size_t)dir * B_ + b) * L_ * L_;
  __shared__ float atts[128][33];
  __shared__ float cpc[32][132];
  __shared__ float asum_s[32];
  const int tid = threadIdx.x;
  for (int i = tid; i < 4096; i += 256)
    atts[i >> 5][i & 31] = attg[(size_t)(i >> 5) * L_ + m0 + (i & 31)];
  __syncthreads();
  if (tid < 32) {
    float s = 0.f;
    for (int l = 0; l < 128; ++l) s += atts[l][tid];
    asum_s[tid] = s;
  }
  const int tm = tid >> 3, t8 = tid & 7;
  float mean_acc[16], max_acc[16];
  #pragma unroll
  for (int i = 0; i < 16; ++i) { mean_acc[i] = 0.f; max_acc[i] = -3.4e38f; }
  for (int lc = 0; lc < 4; ++lc) {
    __syncthreads();
    for (int i = tid; i < 4096; i += 256)
      cpc[i >> 7][i & 127] = cp[(size_t)(lc * 32 + (i >> 7)) * H_ + (i & 127)];
    __syncthreads();
    for (int lq = 0; lq < 32; ++lq) {
      float avv = atts[lc * 32 + lq][tm];
      const float4* cr = (const float4*)&cpc[lq][t8 * 16];
      #pragma unroll
      for (int i = 0; i < 4; ++i) {
        float4 cv = cr[i];
        float t0 = avv * cv.x, t1 = avv * cv.y, t2 = avv * cv.z, t3 = avv * cv.w;
        mean_acc[4*i+0] += t0; max_acc[4*i+0] = fmaxf(max_acc[4*i+0], t0);
        mean_acc[4*i+1] += t1; max_acc[4*i+1] = fmaxf(max_acc[4*i+1], t1);
        mean_acc[4*i+2] += t2; max_acc[4*i+2] = fmaxf(max_acc[4*i+2], t2);
        mean_acc[4*i+3] += t3; max_acc[4*i+3] = fmaxf(max_acc[4*i+3], t3);
      }
    }
  }
  __syncthreads();
  {
    float den = asum_s[tm]; den = (den > EPSV) ? den : EPSV;
    const size_t base = (((size_t)dir * B_ + b) * L_ + m0 + tm) * H_ + t8 * 16;
    #pragma unroll
    for (int i = 0; i < 16; ++i) {
      ameanp[base + i] = mean_acc[i] / den;
      amaxp[base + i] = max_acc[i];
    }
  }
  if (tid < 128) {
    const int p = tid >> 5, mq = tid & 31;
    float mx = -3.4e38f;
    #pragma unroll
    for (int lt = 0; lt < 4; ++lt)
      mx = fmaxf(mx, pcpart[((((size_t)dir * B_ + b) * 4 + lt) * 4 + p) * L_ + m0 + mq]);
    mv[(size_t)(ML_ + b * L_ + m0 + mq) * 32 + (dir ? 20 : 4) + p] = mx;
  }
}

// ---------------- full / att-mean / att-max cosine perspectives. 98304 threads.
__global__ __launch_bounds__(256) void k_mv(
    fp __restrict__ con,
    fp __restrict__ ameanh, fp __restrict__ amaxh,
    fp __restrict__ ameanp, fp __restrict__ amaxp,
    fp w1, fp w2, fp w5, fp w6, fp w7, fp w8,
    float* __restrict__ mv)
{
  int idx = blockIdx.x * 256 + threadIdx.x;
  const int p = idx & 3; int t1 = idx >> 2;
  const int type = t1 % 3; int t2 = t1 / 3;
  const int dir = t2 & 1; int t3 = t2 >> 1;
  const int l = t3 & 127; int t4 = t3 >> 7;
  const int b = t4 & 15; const int side = t4 >> 4;
  const float* v1 = con + (((size_t)(side ? 2 : 0) + dir) * B_ + b) * L_ * H_ + (size_t)l * H_;
  const float* v2;
  if (type == 0) {
    v2 = con + (((size_t)(side ? 0 : 2) + dir) * B_ + b) * L_ * H_ + (size_t)(dir ? 0 : L_ - 1) * H_;
  } else {
    const float* base = (type == 1) ? (side ? ameanp : ameanh) : (side ? amaxp : amaxh);
    v2 = base + (((size_t)dir * B_ + b) * L_ + l) * H_;
  }
  fp w = (type == 0) ? (dir ? w2 : w1) : (type == 1) ? (dir ? w6 : w5) : (dir ? w8 : w7);
  w += p * H_;
  float num = 0.f, s1 = 0.f, s2 = 0.f;
  for (int h = 0; h < H_; ++h) {
    float wv = w[h];
    float a = v1[h] * wv, bb = v2[h] * wv;
    num = fmaf(a, bb, num);
    s1 = fmaf(a, a, s1);
    s2 = fmaf(bb, bb, s2);
  }
  float den = sqrtf(s1) * sqrtf(s2);
  int slot = (type == 0) ? (dir ? 16 : 0) + p : (type == 1) ? (dir ? 24 : 8) + p : (dir ? 28 : 12) + p;
  mv[((size_t)side * ML_ + b * L_ + l) * 32 + slot] = ddiv(num, den);
}

// ---------------- aggregation input projection (K=32). grid (256, 4) block 256.
__global__ __launch_bounds__(256) void k_aggproj(
    fp __restrict__ mv,
    fp Wf, fp Wb, fp bihf, fp bhhf, fp bihb, fp bhhb,
    float* __restrict__ xg)
{
  const int z = blockIdx.y, side = z >> 1, dir = z & 1;
  fp W = dir ? Wb : Wf;
  fp bih = dir ? bihb : bihf;
  fp bhh = dir ? bhhb : bhhf;
  const int r0 = blockIdx.x * 8;
  const float* src = mv + ((size_t)side * ML_ + r0) * 32;
  float* out = xg + ((size_t)z * ML_ + r0) * G_;
  __shared__ float mvs[8][32];
  const int tid = threadIdx.x;
  mvs[tid >> 5][tid & 31] = src[tid];
  __syncthreads();
  float w0[32], w1v[32];
  {
    const float4* wp = (const float4*)(W + (size_t)tid * 32);
    #pragma unroll
    for (int q = 0; q < 8; ++q) {
      float4 u = wp[q];
      w0[4*q+0] = u.x; w0[4*q+1] = u.y; w0[4*q+2] = u.z; w0[4*q+3] = u.w;
    }
    const float4* wp2 = (const float4*)(W + (size_t)(tid + 256) * 32);
    #pragma unroll
    for (int q = 0; q < 8; ++q) {
      float4 u = wp2[q];
      w1v[4*q+0] = u.x; w1v[4*q+1] = u.y; w1v[4*q+2] = u.z; w1v[4*q+3] = u.w;
    }
  }
  float bias0 = bih[tid] + bhh[tid];
  float bias1 = bih[tid + 256] + bhh[tid + 256];
  for (int r = 0; r < 8; ++r) {
    float acc0 = bias0, acc1 = bias1;
    #pragma unroll
    for (int k = 0; k < 32; ++k) {
      float xv = mvs[r][k];
      acc0 = fmaf(w0[k], xv, acc0);
      acc1 = fmaf(w1v[k], xv, acc1);
    }
    out[(size_t)r * G_ + tid] = acc0;
    out[(size_t)r * G_ + tid + 256] = acc1;
  }
}

// ---------------- FC head. grid 16 block 256.
__global__ __launch_bounds__(256) void k_fc(
    fp __restrict__ aggseq,
    fp fc1W, fp fc1b, fp fc2W, fp fc2b,
    float* __restrict__ out)
{
  const int b = blockIdx.x, tid = threadIdx.x;
  __shared__ float x[512];
  __shared__ float y[256];
  for (int i = tid; i < 512; i += 256) {
    int z = i >> 7, h = i & 127;
    int l = (z & 1) ? 0 : (L_ - 1);
    x[i] = aggseq[(((size_t)z * B_ + b) * L_ + l) * H_ + h];
  }
  __syncthreads();
  {
    float acc = fc1b[tid];
    const float4* wr = (const float4*)(fc1W + (size_t)tid * 512);
    const float4* x4 = (const float4*)x;
    #pragma unroll 8
    for (int k4 = 0; k4 < 128; ++k4) {
      float4 u = wr[k4];
      float4 xv = x4[k4];
      acc = fmaf(u.x, xv.x, acc);
      acc = fmaf(u.y, xv.y, acc);
      acc = fmaf(u.z, xv.z, acc);
      acc = fmaf(u.w, xv.w, acc);
    }
    y[tid] = tanh_f(acc);
  }
  __syncthreads();
  if (tid < 2) {
    float acc = fc2b[tid];
    for (int k = 0; k < 256; ++k) acc = fmaf(fc2W[tid * 256 + k], y[k], acc);
    out[b * 2 + tid] = acc;
  }
}

extern "C" void kernel_launch(void* const* d_in, const int* in_sizes, int n_in,
                              void* d_out, int out_size, void* d_ws, size_t ws_size,
                              hipStream_t stream) {
  (void)in_sizes; (void)n_in; (void)out_size; (void)ws_size;
  const int* ta = (const int*)d_in[0];
  const int* tb = (const int*)d_in[1];
  fp emb   = (fp)d_in[2];
  fp cWihf = (fp)d_in[3];
  fp cWhhf = (fp)d_in[4];
  fp cbihf = (fp)d_in[5];
  fp cbhhf = (fp)d_in[6];
  fp cWihb = (fp)d_in[7];
  fp cWhhb = (fp)d_in[8];
  fp cbihb = (fp)d_in[9];
  fp cbhhb = (fp)d_in[10];
  fp aWihf = (fp)d_in[11];
  fp aWhhf = (fp)d_in[12];
  fp abihf = (fp)d_in[13];
  fp abhhf = (fp)d_in[14];
  fp aWihb = (fp)d_in[15];
  fp aWhhb = (fp)d_in[16];
  fp abihb = (fp)d_in[17];
  fp abhhb = (fp)d_in[18];
  fp fc1W  = (fp)d_in[19];
  fp fc1b  = (fp)d_in[20];
  fp fc2W  = (fp)d_in[21];
  fp fc2b  = (fp)d_in[22];
  fp w1 = (fp)d_in[23];
  fp w2 = (fp)d_in[24];
  fp w3 = (fp)d_in[25];
  fp w4 = (fp)d_in[26];
  fp w5 = (fp)d_in[27];
  fp w6 = (fp)d_in[28];
  fp w7 = (fp)d_in[29];
  fp w8 = (fp)d_in[30];

  float* ws = (float*)d_ws;
  float* xg     = ws;                                   // 4*ML*G (reused for agg)
  float* con    = xg     + (size_t)4 * ML_ * G_;        // 4*ML*H
  float* attw   = con    + (size_t)4 * ML_ * H_;        // 2*B*L*L
  float* ameanh = attw   + (size_t)2 * B_ * L_ * L_;    // 2*ML*H
  float* amaxh  = ameanh + (size_t)2 * ML_ * H_;
  float* ameanp = amaxh  + (size_t)2 * ML_ * H_;
  float* amaxp  = ameanp + (size_t)2 * ML_ * H_;
  float* pcpart = amaxp  + (size_t)2 * ML_ * H_;        // 2*B*16*L
  float* mvb    = pcpart + (size_t)2 * B_ * 16 * L_;    // 2*ML*32
  float* aggseq = mvb    + (size_t)2 * ML_ * 32;        // 4*ML*H

  k_proj<<<dim3(32, 8, 4), 256, 0, stream>>>(emb, ta, tb, cWihf, cWihb,
                                             cbihf, cbhhf, cbihb, cbhhb, xg);
  k_lstm<<<dim3(16, 4), 256, 0, stream>>>(xg, cWhhf, cWhhb, con);
  k_att<<<dim3(16, 2, 4), 256, 0, stream>>>(con, w3, w4, attw, ameanh, amaxh, pcpart, mvb);
  k_col<<<dim3(16, 2, 4), 256, 0, stream>>>(con, attw, pcpart, ameanp, amaxp, mvb);
  k_mv<<<384, 256, 0, stream>>>(con, ameanh, amaxh, ameanp, amaxp, w1, w2, w5, w6, w7, w8, mvb);
  k_aggproj<<<dim3(256, 4), 256, 0, stream>>>(mvb, aWihf, aWihb, abihf, abhhf, abihb, abhhb, xg);
  k_lstm<<<dim3(16, 4), 256, 0, stream>>>(xg, aWhhf, aWhhb, aggseq);
  k_fc<<<16, 256, 0, stream>>>(aggseq, fc1W, fc1b, fc2W, fc2b, (float*)d_out);
}

// Round 5
// 503.455 us; speedup vs baseline: 1.3465x; 1.3465x over previous
//
#include <hip/hip_runtime.h>

#define B_ 16
#define L_ 128
#define ML_ 2048
#define E_ 300
#define H_ 128
#define G_ 512
#define EPSV 1e-8f

typedef const float* fp;
typedef __attribute__((ext_vector_type(2))) float f32x2;

__device__ __forceinline__ float sigm(float x) { return 1.f / (1.f + __expf(-x)); }
__device__ __forceinline__ float tanh_f(float x) {
  float e = __expf(-2.f * fabsf(x));
  float r = (1.f - e) / (1.f + e);
  return copysignf(r, x);
}
__device__ __forceinline__ float ddiv(float n, float d) {
  return n / (d > EPSV ? d : EPSV);
}
// packed dual-f32 FMA: d.xy += a.xy * b.xy (VOP3P, gfx90a+). The "v"
// constraints also pin the weight operands into arch VGPRs.
__device__ __forceinline__ void pkfma(f32x2& d, f32x2 a, f32x2 b) {
  asm("v_pk_fma_f32 %0, %1, %2, %0" : "+v"(d) : "v"(a), "v"(b));
}

// ---------------- context input projection: xg[z][m][g] = emb[text] @ W^T + bih + bhh
// grid (32, 8, 4) block 256. z = inp*2 + dir.
__global__ __launch_bounds__(256) void k_proj(
    fp __restrict__ emb,
    const int* __restrict__ ta, const int* __restrict__ tb,
    fp Wf, fp Wb, fp bihf, fp bhhf, fp bihb, fp bhhb,
    float* __restrict__ xg)
{
  const int z = blockIdx.z;
  const int* txt = (z >> 1) ? tb : ta;
  fp W = (z & 1) ? Wb : Wf;
  fp bih = (z & 1) ? bihb : bihf;
  fp bhh = (z & 1) ? bhhb : bhhf;
  float* out = xg + (size_t)z * ML_ * G_;
  const int m0 = blockIdx.x * 64, n0 = blockIdx.y * 64;
  __shared__ float As[12][64];
  __shared__ float Bs[12][64];
  __shared__ int rowidx[64];
  const int tid = threadIdx.x;
  if (tid < 64) rowidx[tid] = txt[m0 + tid];
  __syncthreads();
  const int tm = tid >> 4, tn = tid & 15;
  float acc[4][4] = {};
  for (int k0 = 0; k0 < 300; k0 += 12) {
    for (int i = tid; i < 768; i += 256) {
      int m = i / 12, k = i - m * 12;
      As[k][m] = emb[(size_t)rowidx[m] * 300 + k0 + k];
    }
    for (int i = tid; i < 768; i += 256) {
      int n = i / 12, k = i - n * 12;
      Bs[k][n] = W[(size_t)(n0 + n) * 300 + k0 + k];
    }
    __syncthreads();
    #pragma unroll
    for (int k = 0; k < 12; ++k) {
      float4 a = *(const float4*)&As[k][tm * 4];
      float4 bv = *(const float4*)&Bs[k][tn * 4];
      float aa[4] = {a.x, a.y, a.z, a.w};
      #pragma unroll
      for (int i = 0; i < 4; ++i) {
        acc[i][0] = fmaf(aa[i], bv.x, acc[i][0]);
        acc[i][1] = fmaf(aa[i], bv.y, acc[i][1]);
        acc[i][2] = fmaf(aa[i], bv.z, acc[i][2]);
        acc[i][3] = fmaf(aa[i], bv.w, acc[i][3]);
      }
    }
    __syncthreads();
  }
  float biasv[4];
  #pragma unroll
  for (int j = 0; j < 4; ++j)
    biasv[j] = bih[n0 + tn * 4 + j] + bhh[n0 + tn * 4 + j];
  #pragma unroll
  for (int i = 0; i < 4; ++i) {
    float* row = out + (size_t)(m0 + tm * 4 + i) * G_ + n0 + tn * 4;
    #pragma unroll
    for (int j = 0; j < 4; ++j) row[j] = acc[i][j] + biasv[j];
  }
}

// ---------------- LSTM scan. grid (16, 4) block 512. One WG per (z, b) scan.
// Round-5 layout: lane l -> kh=l&1 (k-half), ph=(l>>1)&1 (row pair: (i,g) or
// (f,o)), j = wave*16 + (l>>2). Each thread: 2 rows x 64 weights = 128 VGPR
// -> 2 waves/SIMD (round-4 cliff was 256 VGPR -> 1 wave/SIMD). Per-wave LDS
// traffic: 16 ds_read_b128/step (2-address reads are conflict-free). k-half
// combine shfl_xor(1); gate exchange shfl_xor(2); ONE barrier/step.
__global__ __launch_bounds__(512, 2) void k_lstm(
    fp __restrict__ xg, fp Whhf, fp Whhb, float* __restrict__ out)
{
  const int b = blockIdx.x, z = blockIdx.y, dir = z & 1;
  fp Whh = dir ? Whhb : Whhf;
  fp __restrict__ xgz = xg + ((size_t)z * ML_ + (size_t)b * L_) * G_;
  float* __restrict__ outz = out + ((size_t)z * ML_ + (size_t)b * L_) * H_;
  const int tid = threadIdx.x;
  const int wv = tid >> 6, l = tid & 63;
  const int kh = l & 1, ph = (l >> 1) & 1, jj = l >> 2;
  const int j = wv * 16 + jj;
  const int rA = ph * H_ + j;        // i_j (ph=0) or f_j (ph=1)
  const int rB = rA + 2 * H_;        // g_j (ph=0) or o_j (ph=1)
  f32x2 wA[32], wB[32];
  {
    const float4* pA = (const float4*)(Whh + (size_t)rA * H_ + kh * 64);
    const float4* pB = (const float4*)(Whh + (size_t)rB * H_ + kh * 64);
    float4* dA = (float4*)wA; float4* dB = (float4*)wB;
    #pragma unroll
    for (int q = 0; q < 16; ++q) dA[q] = pA[q];
    #pragma unroll
    for (int q = 0; q < 16; ++q) dB[q] = pB[q];
  }
  __shared__ float hs[2][128];
  if (tid < 128) hs[0][tid] = 0.f;
  float c = 0.f;   // replicated across the 4 (kh,ph) lanes of each j
  const int pos0 = dir ? (L_ - 1) : 0;
  float xvA = xgz[(size_t)pos0 * G_ + rA];
  float xvB = xgz[(size_t)pos0 * G_ + rB];
  __syncthreads();
  int cur = 0;
  for (int t = 0; t < L_; ++t) {
    const int pos = dir ? (L_ - 1 - t) : t;
    const int tnext = (t + 1 < L_) ? (t + 1) : t;
    const int posn = dir ? (L_ - 1 - tnext) : tnext;
    float xvA_n = xgz[(size_t)posn * G_ + rA];
    float xvB_n = xgz[(size_t)posn * G_ + rB];
    f32x2 accA0 = {0.f, 0.f}, accA1 = {0.f, 0.f};
    f32x2 accB0 = {0.f, 0.f}, accB1 = {0.f, 0.f};
    const float4* h4 = (const float4*)(&hs[cur][kh * 64]);
    #pragma unroll
    for (int q = 0; q < 16; ++q) {
      float4 hv = h4[q];
      f32x2 hlo; hlo.x = hv.x; hlo.y = hv.y;
      f32x2 hhi; hhi.x = hv.z; hhi.y = hv.w;
      pkfma(accA0, wA[2 * q],     hlo);
      pkfma(accA1, wA[2 * q + 1], hhi);
      pkfma(accB0, wB[2 * q],     hlo);
      pkfma(accB1, wB[2 * q + 1], hhi);
    }
    float aA = (accA0.x + accA0.y) + (accA1.x + accA1.y);
    float aB = (accB0.x + accB0.y) + (accB1.x + accB1.y);
    aA += __shfl_xor(aA, 1, 64);   // combine k-halves
    aB += __shfl_xor(aB, 1, 64);
    aA += xvA; aB += xvB;
    float actA = sigm(aA);                       // i (ph=0) or f (ph=1)
    float actB = ph ? sigm(aB) : tanh_f(aB);     // o (ph=1) or g (ph=0)
    float exA = __shfl_xor(actA, 2, 64);
    float exB = __shfl_xor(actB, 2, 64);
    float iv = ph ? exA : actA;
    float fv = ph ? actA : exA;
    float gv = ph ? exB : actB;
    float ov = ph ? actB : exB;
    c = fmaf(fv, c, iv * gv);
    float hn = ov * tanh_f(c);
    const int nxt = cur ^ 1;
    if ((l & 3) == 0) {
      hs[nxt][j] = hn;
      outz[(size_t)pos * H_ + j] = hn;
    }
    asm volatile("s_waitcnt lgkmcnt(0)" ::: "memory");
    __builtin_amdgcn_s_barrier();
    cur = nxt; xvA = xvA_n; xvB = xvB_n;
  }
}

// ---------------- attention + pairwise rows. grid (16, 2, 4) block 256.
__global__ __launch_bounds__(256) void k_att(
    fp __restrict__ con, fp w3, fp w4,
    float* __restrict__ att, float* __restrict__ ameanh, float* __restrict__ amaxh,
    float* __restrict__ pcpart, float* __restrict__ mv)
{
  const int b = blockIdx.x, dir = blockIdx.y, lt = blockIdx.z;
  const int l0 = lt * 32;
  fp __restrict__ cp = con + ((size_t)dir * B_ + b) * L_ * H_;
  fp __restrict__ ch = con + ((size_t)(2 + dir) * B_ + b) * L_ * H_;
  fp w = dir ? w4 : w3;
  float* __restrict__ attg = att + ((size_t)dir * B_ + b) * L_ * L_;
  __shared__ float cps[32][132];
  __shared__ float chs[32][132];
  __shared__ float w2s[4][128];
  __shared__ float attb[32][33];
  __shared__ float pcb[4][32][33];
  __shared__ float n0l[32], nql[4][32], n0m[32], nqm[4][32], asum_s[32];
  const int tid = threadIdx.x;
  for (int i = tid; i < 512; i += 256) {
    float wv = w[i];
    w2s[i >> 7][i & 127] = wv * wv;
  }
  for (int i = tid; i < 4096; i += 256)
    cps[i >> 7][i & 127] = cp[(size_t)(l0 + (i >> 7)) * H_ + (i & 127)];
  __syncthreads();
  for (int d = tid; d < 160; d += 256) {
    int l = d / 5, q = d - l * 5;
    const float4* vr = (const float4*)&cps[l][0];
    float s = 0.f;
    if (q == 0) {
      #pragma unroll 8
      for (int h4 = 0; h4 < 32; ++h4) {
        float4 v = vr[h4];
        s += v.x*v.x + v.y*v.y + v.z*v.z + v.w*v.w;
      }
      n0l[l] = sqrtf(s);
    } else {
      const float4* wr = (const float4*)&w2s[q - 1][0];
      #pragma unroll 8
      for (int h4 = 0; h4 < 32; ++h4) {
        float4 v = vr[h4]; float4 ww = wr[h4];
        s += v.x*v.x*ww.x + v.y*v.y*ww.y + v.z*v.z*ww.z + v.w*v.w*ww.w;
      }
      nql[q - 1][l] = sqrtf(s);
    }
  }
  const int tl = tid >> 3, t8 = tid & 7;
  float amean_acc[16], amax_acc[16];
  #pragma unroll
  for (int i = 0; i < 16; ++i) { amean_acc[i] = 0.f; amax_acc[i] = -3.4e38f; }
  float asum_reg = 0.f;
  float pmax_reg = -3.4e38f;
  for (int mc = 0; mc < 4; ++mc) {
    __syncthreads();
    for (int i = tid; i < 4096; i += 256)
      chs[i >> 7][i & 127] = ch[(size_t)(mc * 32 + (i >> 7)) * H_ + (i & 127)];
    __syncthreads();
    for (int d = tid; d < 160; d += 256) {
      int m = d / 5, q = d - m * 5;
      const float4* vr = (const float4*)&chs[m][0];
      float s = 0.f;
      if (q == 0) {
        #pragma unroll 8
        for (int h4 = 0; h4 < 32; ++h4) {
          float4 v = vr[h4];
          s += v.x*v.x + v.y*v.y + v.z*v.z + v.w*v.w;
        }
        n0m[m] = sqrtf(s);
      } else {
        const float4* wr = (const float4*)&w2s[q - 1][0];
        #pragma unroll 8
        for (int h4 = 0; h4 < 32; ++h4) {
          float4 v = vr[h4]; float4 ww = wr[h4];
          s += v.x*v.x*ww.x + v.y*v.y*ww.y + v.z*v.z*ww.z + v.w*v.w*ww.w;
        }
        nqm[q - 1][m] = sqrtf(s);
      }
    }
    __syncthreads();
    // phase A: gram rows for {1, w0..w3} weightings
    float a0[4], ap0[4], ap1[4], ap2[4], ap3[4];
    #pragma unroll
    for (int mm = 0; mm < 4; ++mm) { a0[mm]=0.f; ap0[mm]=0.f; ap1[mm]=0.f; ap2[mm]=0.f; ap3[mm]=0.f; }
    #pragma unroll 4
    for (int h4 = 0; h4 < 32; ++h4) {
      const float4 av = *(const float4*)&cps[tl][h4 * 4];
      const float4 q0 = *(const float4*)&w2s[0][h4 * 4];
      const float4 q1 = *(const float4*)&w2s[1][h4 * 4];
      const float4 q2 = *(const float4*)&w2s[2][h4 * 4];
      const float4 q3 = *(const float4*)&w2s[3][h4 * 4];
      #pragma unroll
      for (int mm = 0; mm < 4; ++mm) {
        const float4 cv = *(const float4*)&chs[t8 * 4 + mm][h4 * 4];
        float px = av.x * cv.x, py = av.y * cv.y, pz = av.z * cv.z, pw = av.w * cv.w;
        a0[mm] += (px + py) + (pz + pw);
        ap0[mm] += px * q0.x + py * q0.y + pz * q0.z + pw * q0.w;
        ap1[mm] += px * q1.x + py * q1.y + pz * q1.z + pw * q1.w;
        ap2[mm] += px * q2.x + py * q2.y + pz * q2.z + pw * q2.w;
        ap3[mm] += px * q3.x + py * q3.y + pz * q3.z + pw * q3.w;
      }
    }
    #pragma unroll
    for (int mm = 0; mm < 4; ++mm) {
      const int m = t8 * 4 + mm;
      float attv = ddiv(a0[mm], n0l[tl] * n0m[m]);
      attb[tl][m] = attv;
      attg[(size_t)(l0 + tl) * L_ + mc * 32 + m] = attv;
      pcb[0][tl][m] = ddiv(ap0[mm], nql[0][tl] * nqm[0][m]);
      pcb[1][tl][m] = ddiv(ap1[mm], nql[1][tl] * nqm[1][m]);
      pcb[2][tl][m] = ddiv(ap2[mm], nql[2][tl] * nqm[2][m]);
      pcb[3][tl][m] = ddiv(ap3[mm], nql[3][tl] * nqm[3][m]);
    }
    __syncthreads();
    // phase B: row reductions over this m-chunk
    for (int mq = 0; mq < 32; ++mq) {
      float avv = attb[tl][mq];
      const float4* cr = (const float4*)&chs[mq][t8 * 16];
      #pragma unroll
      for (int i = 0; i < 4; ++i) {
        float4 cv = cr[i];
        float t0 = avv * cv.x, t1 = avv * cv.y, t2 = avv * cv.z, t3 = avv * cv.w;
        amean_acc[4*i+0] += t0; amax_acc[4*i+0] = fmaxf(amax_acc[4*i+0], t0);
        amean_acc[4*i+1] += t1; amax_acc[4*i+1] = fmaxf(amax_acc[4*i+1], t1);
        amean_acc[4*i+2] += t2; amax_acc[4*i+2] = fmaxf(amax_acc[4*i+2], t2);
        amean_acc[4*i+3] += t3; amax_acc[4*i+3] = fmaxf(amax_acc[4*i+3], t3);
      }
    }
    if (tid < 32) {
      float s = 0.f;
      for (int mq = 0; mq < 32; ++mq) s += attb[tid][mq];
      asum_reg += s;
    }
    if (tid < 128) {
      const int p = tid >> 5, q = tid & 31;
      float mx = pmax_reg;
      for (int mq = 0; mq < 32; ++mq) mx = fmaxf(mx, pcb[p][q][mq]);
      pmax_reg = mx;
      float mx2 = -3.4e38f;
      for (int lq = 0; lq < 32; ++lq) mx2 = fmaxf(mx2, pcb[p][lq][q]);
      pcpart[((((size_t)dir * B_ + b) * 4 + lt) * 4 + p) * L_ + mc * 32 + q] = mx2;
    }
    __syncthreads();
  }
  if (tid < 32) asum_s[tid] = asum_reg;
  __syncthreads();
  {
    float den = asum_s[tl]; den = (den > EPSV) ? den : EPSV;
    const size_t base = (((size_t)dir * B_ + b) * L_ + l0 + tl) * H_ + t8 * 16;
    #pragma unroll
    for (int i = 0; i < 16; ++i) {
      ameanh[base + i] = amean_acc[i] / den;
      amaxh[base + i] = amax_acc[i];
    }
  }
  if (tid < 128) {
    const int p = tid >> 5, lq = tid & 31;
    mv[(size_t)(b * L_ + l0 + lq) * 32 + (dir ? 20 : 4) + p] = pmax_reg;
  }
}

// ---------------- column reductions. grid (16, 2, 4) block 256.
__global__ __launch_bounds__(256) void k_col(
    fp __restrict__ con, fp __restrict__ att,
    fp __restrict__ pcpart,
    float* __restrict__ ameanp, float* __restrict__ amaxp, float* __restrict__ mv)
{
  const int b = blockIdx.x, dir = blockIdx.y, mt = blockIdx.z;
  const int m0 = mt * 32;
  fp __restrict__ cp = con + ((size_t)dir * B_ + b) * L_ * H_;
  fp __restrict__ attg = att + ((size_t)dir * B_ + b) * L_ * L_;
  __shared__ float atts[128][33];
  __shared__ float cpc[32][132];
  __shared__ float asum_s[32];
  const int tid = threadIdx.x;
  for (int i = tid; i < 4096; i += 256)
    atts[i >> 5][i & 31] = attg[(size_t)(i >> 5) * L_ + m0 + (i & 31)];
  __syncthreads();
  if (tid < 32) {
    float s = 0.f;
    for (int l = 0; l < 128; ++l) s += atts[l][tid];
    asum_s[tid] = s;
  }
  const int tm = tid >> 3, t8 = tid & 7;
  float mean_acc[16], max_acc[16];
  #pragma unroll
  for (int i = 0; i < 16; ++i) { mean_acc[i] = 0.f; max_acc[i] = -3.4e38f; }
  for (int lc = 0; lc < 4; ++lc) {
    __syncthreads();
    for (int i = tid; i < 4096; i += 256)
      cpc[i >> 7][i & 127] = cp[(size_t)(lc * 32 + (i >> 7)) * H_ + (i & 127)];
    __syncthreads();
    for (int lq = 0; lq < 32; ++lq) {
      float avv = atts[lc * 32 + lq][tm];
      const float4* cr = (const float4*)&cpc[lq][t8 * 16];
      #pragma unroll
      for (int i = 0; i < 4; ++i) {
        float4 cv = cr[i];
        float t0 = avv * cv.x, t1 = avv * cv.y, t2 = avv * cv.z, t3 = avv * cv.w;
        mean_acc[4*i+0] += t0; max_acc[4*i+0] = fmaxf(max_acc[4*i+0], t0);
        mean_acc[4*i+1] += t1; max_acc[4*i+1] = fmaxf(max_acc[4*i+1], t1);
        mean_acc[4*i+2] += t2; max_acc[4*i+2] = fmaxf(max_acc[4*i+2], t2);
        mean_acc[4*i+3] += t3; max_acc[4*i+3] = fmaxf(max_acc[4*i+3], t3);
      }
    }
  }
  __syncthreads();
  {
    float den = asum_s[tm]; den = (den > EPSV) ? den : EPSV;
    const size_t base = (((size_t)dir * B_ + b) * L_ + m0 + tm) * H_ + t8 * 16;
    #pragma unroll
    for (int i = 0; i < 16; ++i) {
      ameanp[base + i] = mean_acc[i] / den;
      amaxp[base + i] = max_acc[i];
    }
  }
  if (tid < 128) {
    const int p = tid >> 5, mq = tid & 31;
    float mx = -3.4e38f;
    #pragma unroll
    for (int lt = 0; lt < 4; ++lt)
      mx = fmaxf(mx, pcpart[((((size_t)dir * B_ + b) * 4 + lt) * 4 + p) * L_ + m0 + mq]);
    mv[(size_t)(ML_ + b * L_ + m0 + mq) * 32 + (dir ? 20 : 4) + p] = mx;
  }
}

// ---------------- full / att-mean / att-max cosine perspectives. 98304 threads.
__global__ __launch_bounds__(256) void k_mv(
    fp __restrict__ con,
    fp __restrict__ ameanh, fp __restrict__ amaxh,
    fp __restrict__ ameanp, fp __restrict__ amaxp,
    fp w1, fp w2, fp w5, fp w6, fp w7, fp w8,
    float* __restrict__ mv)
{
  int idx = blockIdx.x * 256 + threadIdx.x;
  const int p = idx & 3; int t1 = idx >> 2;
  const int type = t1 % 3; int t2 = t1 / 3;
  const int dir = t2 & 1; int t3 = t2 >> 1;
  const int l = t3 & 127; int t4 = t3 >> 7;
  const int b = t4 & 15; const int side = t4 >> 4;
  const float* v1 = con + (((size_t)(side ? 2 : 0) + dir) * B_ + b) * L_ * H_ + (size_t)l * H_;
  const float* v2;
  if (type == 0) {
    v2 = con + (((size_t)(side ? 0 : 2) + dir) * B_ + b) * L_ * H_ + (size_t)(dir ? 0 : L_ - 1) * H_;
  } else {
    const float* base = (type == 1) ? (side ? ameanp : ameanh) : (side ? amaxp : amaxh);
    v2 = base + (((size_t)dir * B_ + b) * L_ + l) * H_;
  }
  fp w = (type == 0) ? (dir ? w2 : w1) : (type == 1) ? (dir ? w6 : w5) : (dir ? w8 : w7);
  w += p * H_;
  float num = 0.f, s1 = 0.f, s2 = 0.f;
  for (int h = 0; h < H_; ++h) {
    float wv = w[h];
    float a = v1[h] * wv, bb = v2[h] * wv;
    num = fmaf(a, bb, num);
    s1 = fmaf(a, a, s1);
    s2 = fmaf(bb, bb, s2);
  }
  float den = sqrtf(s1) * sqrtf(s2);
  int slot = (type == 0) ? (dir ? 16 : 0) + p : (type == 1) ? (dir ? 24 : 8) + p : (dir ? 28 : 12) + p;
  mv[((size_t)side * ML_ + b * L_ + l) * 32 + slot] = ddiv(num, den);
}

// ---------------- aggregation input projection (K=32). grid (256, 4) block 256.
__global__ __launch_bounds__(256) void k_aggproj(
    fp __restrict__ mv,
    fp Wf, fp Wb, fp bihf, fp bhhf, fp bihb, fp bhhb,
    float* __restrict__ xg)
{
  const int z = blockIdx.y, side = z >> 1, dir = z & 1;
  fp W = dir ? Wb : Wf;
  fp bih = dir ? bihb : bihf;
  fp bhh = dir ? bhhb : bhhf;
  const int r0 = blockIdx.x * 8;
  const float* src = mv + ((size_t)side * ML_ + r0) * 32;
  float* out = xg + ((size_t)z * ML_ + r0) * G_;
  __shared__ float mvs[8][32];
  const int tid = threadIdx.x;
  mvs[tid >> 5][tid & 31] = src[tid];
  __syncthreads();
  float w0[32], w1v[32];
  {
    const float4* wp = (const float4*)(W + (size_t)tid * 32);
    #pragma unroll
    for (int q = 0; q < 8; ++q) {
      float4 u = wp[q];
      w0[4*q+0] = u.x; w0[4*q+1] = u.y; w0[4*q+2] = u.z; w0[4*q+3] = u.w;
    }
    const float4* wp2 = (const float4*)(W + (size_t)(tid + 256) * 32);
    #pragma unroll
    for (int q = 0; q < 8; ++q) {
      float4 u = wp2[q];
      w1v[4*q+0] = u.x; w1v[4*q+1] = u.y; w1v[4*q+2] = u.z; w1v[4*q+3] = u.w;
    }
  }
  float bias0 = bih[tid] + bhh[tid];
  float bias1 = bih[tid + 256] + bhh[tid + 256];
  for (int r = 0; r < 8; ++r) {
    float acc0 = bias0, acc1 = bias1;
    #pragma unroll
    for (int k = 0; k < 32; ++k) {
      float xv = mvs[r][k];
      acc0 = fmaf(w0[k], xv, acc0);
      acc1 = fmaf(w1v[k], xv, acc1);
    }
    out[(size_t)r * G_ + tid] = acc0;
    out[(size_t)r * G_ + tid + 256] = acc1;
  }
}

// ---------------- FC head. grid 16 block 256.
__global__ __launch_bounds__(256) void k_fc(
    fp __restrict__ aggseq,
    fp fc1W, fp fc1b, fp fc2W, fp fc2b,
    float* __restrict__ out)
{
  const int b = blockIdx.x, tid = threadIdx.x;
  __shared__ float x[512];
  __shared__ float y[256];
  for (int i = tid; i < 512; i += 256) {
    int z = i >> 7, h = i & 127;
    int l = (z & 1) ? 0 : (L_ - 1);
    x[i] = aggseq[(((size_t)z * B_ + b) * L_ + l) * H_ + h];
  }
  __syncthreads();
  {
    float acc = fc1b[tid];
    const float4* wr = (const float4*)(fc1W + (size_t)tid * 512);
    const float4* x4 = (const float4*)x;
    #pragma unroll 8
    for (int k4 = 0; k4 < 128; ++k4) {
      float4 u = wr[k4];
      float4 xv = x4[k4];
      acc = fmaf(u.x, xv.x, acc);
      acc = fmaf(u.y, xv.y, acc);
      acc = fmaf(u.z, xv.z, acc);
      acc = fmaf(u.w, xv.w, acc);
    }
    y[tid] = tanh_f(acc);
  }
  __syncthreads();
  if (tid < 2) {
    float acc = fc2b[tid];
    for (int k = 0; k < 256; ++k) acc = fmaf(fc2W[tid * 256 + k], y[k], acc);
    out[b * 2 + tid] = acc;
  }
}

extern "C" void kernel_launch(void* const* d_in, const int* in_sizes, int n_in,
                              void* d_out, int out_size, void* d_ws, size_t ws_size,
                              hipStream_t stream) {
  (void)in_sizes; (void)n_in; (void)out_size; (void)ws_size;
  const int* ta = (const int*)d_in[0];
  const int* tb = (const int*)d_in[1];
  fp emb   = (fp)d_in[2];
  fp cWihf = (fp)d_in[3];
  fp cWhhf = (fp)d_in[4];
  fp cbihf = (fp)d_in[5];
  fp cbhhf = (fp)d_in[6];
  fp cWihb = (fp)d_in[7];
  fp cWhhb = (fp)d_in[8];
  fp cbihb = (fp)d_in[9];
  fp cbhhb = (fp)d_in[10];
  fp aWihf = (fp)d_in[11];
  fp aWhhf = (fp)d_in[12];
  fp abihf = (fp)d_in[13];
  fp abhhf = (fp)d_in[14];
  fp aWihb = (fp)d_in[15];
  fp aWhhb = (fp)d_in[16];
  fp abihb = (fp)d_in[17];
  fp abhhb = (fp)d_in[18];
  fp fc1W  = (fp)d_in[19];
  fp fc1b  = (fp)d_in[20];
  fp fc2W  = (fp)d_in[21];
  fp fc2b  = (fp)d_in[22];
  fp w1 = (fp)d_in[23];
  fp w2 = (fp)d_in[24];
  fp w3 = (fp)d_in[25];
  fp w4 = (fp)d_in[26];
  fp w5 = (fp)d_in[27];
  fp w6 = (fp)d_in[28];
  fp w7 = (fp)d_in[29];
  fp w8 = (fp)d_in[30];

  float* ws = (float*)d_ws;
  float* xg     = ws;                                   // 4*ML*G (reused for agg)
  float* con    = xg     + (size_t)4 * ML_ * G_;        // 4*ML*H
  float* attw   = con    + (size_t)4 * ML_ * H_;        // 2*B*L*L
  float* ameanh = attw   + (size_t)2 * B_ * L_ * L_;    // 2*ML*H
  float* amaxh  = ameanh + (size_t)2 * ML_ * H_;
  float* ameanp = amaxh  + (size_t)2 * ML_ * H_;
  float* amaxp  = ameanp + (size_t)2 * ML_ * H_;
  float* pcpart = amaxp  + (size_t)2 * ML_ * H_;        // 2*B*16*L
  float* mvb    = pcpart + (size_t)2 * B_ * 16 * L_;    // 2*ML*32
  float* aggseq = mvb    + (size_t)2 * ML_ * 32;        // 4*ML*H

  k_proj<<<dim3(32, 8, 4), 256, 0, stream>>>(emb, ta, tb, cWihf, cWihb,
                                             cbihf, cbhhf, cbihb, cbhhb, xg);
  k_lstm<<<dim3(16, 4), 512, 0, stream>>>(xg, cWhhf, cWhhb, con);
  k_att<<<dim3(16, 2, 4), 256, 0, stream>>>(con, w3, w4, attw, ameanh, amaxh, pcpart, mvb);
  k_col<<<dim3(16, 2, 4), 256, 0, stream>>>(con, attw, pcpart, ameanp, amaxp, mvb);
  k_mv<<<384, 256, 0, stream>>>(con, ameanh, amaxh, ameanp, amaxp, w1, w2, w5, w6, w7, w8, mvb);
  k_aggproj<<<dim3(256, 4), 256, 0, stream>>>(mvb, aWihf, aWihb, abihf, abhhf, abihb, abhhb, xg);
  k_lstm<<<dim3(16, 4), 512, 0, stream>>>(xg, aWhhf, aWhhb, aggseq);
  k_fc<<<16, 256, 0, stream>>>(aggseq, fc1W, fc1b, fc2W, fc2b, (float*)d_out);
}

// Round 6
// 479.501 us; speedup vs baseline: 1.4137x; 1.0500x over previous
//
#include <hip/hip_runtime.h>

#define B_ 16
#define L_ 128
#define ML_ 2048
#define E_ 300
#define H_ 128
#define G_ 512
#define EPSV 1e-8f

typedef const float* fp;
typedef __attribute__((ext_vector_type(2))) float f32x2;

__device__ __forceinline__ float sigm(float x) { return 1.f / (1.f + __expf(-x)); }
__device__ __forceinline__ float tanh_f(float x) {
  float e = __expf(-2.f * fabsf(x));
  float r = (1.f - e) / (1.f + e);
  return copysignf(r, x);
}
__device__ __forceinline__ float ddiv(float n, float d) {
  return n / (d > EPSV ? d : EPSV);
}
// packed dual-f32 FMA: d.xy += a.xy * b.xy (VOP3P).
__device__ __forceinline__ void pkfma(f32x2& d, f32x2 a, f32x2 b) {
  asm("v_pk_fma_f32 %0, %1, %2, %0" : "+v"(d) : "v"(a), "v"(b));
}

// ---------------- context input projection: xg[z][m][g] = emb[text] @ W^T + bih + bhh
// grid (32, 8, 4) block 256. z = inp*2 + dir.
__global__ __launch_bounds__(256) void k_proj(
    fp __restrict__ emb,
    const int* __restrict__ ta, const int* __restrict__ tb,
    fp Wf, fp Wb, fp bihf, fp bhhf, fp bihb, fp bhhb,
    float* __restrict__ xg)
{
  const int z = blockIdx.z;
  const int* txt = (z >> 1) ? tb : ta;
  fp W = (z & 1) ? Wb : Wf;
  fp bih = (z & 1) ? bihb : bihf;
  fp bhh = (z & 1) ? bhhb : bhhf;
  float* out = xg + (size_t)z * ML_ * G_;
  const int m0 = blockIdx.x * 64, n0 = blockIdx.y * 64;
  __shared__ float As[12][64];
  __shared__ float Bs[12][64];
  __shared__ int rowidx[64];
  const int tid = threadIdx.x;
  if (tid < 64) rowidx[tid] = txt[m0 + tid];
  __syncthreads();
  const int tm = tid >> 4, tn = tid & 15;
  float acc[4][4] = {};
  for (int k0 = 0; k0 < 300; k0 += 12) {
    for (int i = tid; i < 768; i += 256) {
      int m = i / 12, k = i - m * 12;
      As[k][m] = emb[(size_t)rowidx[m] * 300 + k0 + k];
    }
    for (int i = tid; i < 768; i += 256) {
      int n = i / 12, k = i - n * 12;
      Bs[k][n] = W[(size_t)(n0 + n) * 300 + k0 + k];
    }
    __syncthreads();
    #pragma unroll
    for (int k = 0; k < 12; ++k) {
      float4 a = *(const float4*)&As[k][tm * 4];
      float4 bv = *(const float4*)&Bs[k][tn * 4];
      float aa[4] = {a.x, a.y, a.z, a.w};
      #pragma unroll
      for (int i = 0; i < 4; ++i) {
        acc[i][0] = fmaf(aa[i], bv.x, acc[i][0]);
        acc[i][1] = fmaf(aa[i], bv.y, acc[i][1]);
        acc[i][2] = fmaf(aa[i], bv.z, acc[i][2]);
        acc[i][3] = fmaf(aa[i], bv.w, acc[i][3]);
      }
    }
    __syncthreads();
  }
  float biasv[4];
  #pragma unroll
  for (int j = 0; j < 4; ++j)
    biasv[j] = bih[n0 + tn * 4 + j] + bhh[n0 + tn * 4 + j];
  #pragma unroll
  for (int i = 0; i < 4; ++i) {
    float* row = out + (size_t)(m0 + tm * 4 + i) * G_ + n0 + tn * 4;
    #pragma unroll
    for (int j = 0; j < 4; ++j) row[j] = acc[i][j] + biasv[j];
  }
}

// ---------------- LSTM scan. grid (16, 4) block 512. One WG per (z, b) scan.
// Round-6: k-split-4 reduce-scatter. Lane l: kh=l&3 owns h-quarter
// [kh*32,kh*32+32), rg=l>>2 -> j=w*16+rg. Thread holds 4 gate-rows x 32 k
// (128 f32). Per step per wave: 2 ds_read_b128 (vs 16 in r5, 32 in r2 --
// LDS pipe was the wall: 4.19M bank-conflict cycles, ~2300 cyc/step),
// 3-shfl butterfly reduce-scatter (lane kh ends owning gate kh of row j),
// activation, 3-shfl gate exchange, replicated c, ONE barrier (hs dbuf).
__global__ __launch_bounds__(512, 2) void k_lstm(
    fp __restrict__ xg, fp Whhf, fp Whhb, float* __restrict__ out)
{
  const int b = blockIdx.x, z = blockIdx.y, dir = z & 1;
  fp Whh = dir ? Whhb : Whhf;
  fp __restrict__ xgz = xg + ((size_t)z * ML_ + (size_t)b * L_) * G_;
  float* __restrict__ outz = out + ((size_t)z * ML_ + (size_t)b * L_) * H_;
  const int tid = threadIdx.x;
  const int wv = tid >> 6, l = tid & 63;
  const int kh = l & 3, rg = l >> 2;
  const int j = wv * 16 + rg;
  const int b0 = kh & 1, b1 = (kh >> 1) & 1;
  // 4 gate rows (i,f,g,o for hidden j), 32-k slice each: 128 f32 in regs
  float4 wq[4][8];
  #pragma unroll
  for (int g = 0; g < 4; ++g) {
    const float4* p = (const float4*)(Whh + (size_t)(g * 128 + j) * H_ + kh * 32);
    #pragma unroll
    for (int q = 0; q < 8; ++q) wq[g][q] = p[q];
  }
  __shared__ float hs[2][128];
  if (tid < 128) hs[0][tid] = 0.f;
  float c = 0.f;   // replicated across the 4 kh lanes of each j
  const int pos0 = dir ? (L_ - 1) : 0;
  // this lane only needs the xg entry for gate kh, row j
  float xv = xgz[(size_t)pos0 * G_ + kh * 128 + j];
  __syncthreads();
  int cur = 0;
  for (int t = 0; t < L_; ++t) {
    const int pos = dir ? (L_ - 1 - t) : t;
    const int tnx = (t + 1 < L_) ? (t + 1) : t;
    const int posn = dir ? (L_ - 1 - tnx) : tnx;
    float xvn = xgz[(size_t)posn * G_ + kh * 128 + j];
    // 4 gate partial dots over this lane's 32-float h quarter
    f32x2 a2[4];
    #pragma unroll
    for (int g = 0; g < 4; ++g) { a2[g].x = 0.f; a2[g].y = 0.f; }
    const float4* h4 = (const float4*)(&hs[cur][kh * 32]);
    #pragma unroll
    for (int q = 0; q < 8; ++q) {
      float4 hv = h4[q];
      f32x2 hlo; hlo.x = hv.x; hlo.y = hv.y;
      f32x2 hhi; hhi.x = hv.z; hhi.y = hv.w;
      #pragma unroll
      for (int g = 0; g < 4; ++g) {
        float4 wqv = wq[g][q];
        f32x2 wlo; wlo.x = wqv.x; wlo.y = wqv.y;
        f32x2 whi; whi.x = wqv.z; whi.y = wqv.w;
        pkfma(a2[g], wlo, hlo);
        pkfma(a2[g], whi, hhi);
      }
    }
    float pg0 = a2[0].x + a2[0].y;
    float pg1 = a2[1].x + a2[1].y;
    float pg2 = a2[2].x + a2[2].y;
    float pg3 = a2[3].x + a2[3].y;
    // butterfly reduce-scatter over the 4 kh lanes: lane kh ends with gate kh
    float sendA = b0 ? pg0 : pg1;
    float sendB = b0 ? pg2 : pg3;
    float keepA = b0 ? pg1 : pg0;
    float keepB = b0 ? pg3 : pg2;
    float uA = keepA + __shfl_xor(sendA, 1, 64);
    float uB = keepB + __shfl_xor(sendB, 1, 64);
    float mine  = b1 ? uB : uA;
    float send2 = b1 ? uA : uB;
    float tot = mine + __shfl_xor(send2, 2, 64);
    float pre = tot + xv;
    float act = (kh == 2) ? tanh_f(pre) : sigm(pre);
    // gate exchange among the 4 kh lanes
    float e1 = __shfl_xor(act, 1, 64);
    float e2 = __shfl_xor(act, 2, 64);
    float e3 = __shfl_xor(e1, 2, 64);
    float iv = (kh == 0) ? act : (kh == 1) ? e1 : (kh == 2) ? e2 : e3;
    float fv = (kh == 0) ? e1 : (kh == 1) ? act : (kh == 2) ? e3 : e2;
    float gv = (kh == 0) ? e2 : (kh == 1) ? e3 : (kh == 2) ? act : e1;
    float ov = (kh == 0) ? e3 : (kh == 1) ? e2 : (kh == 2) ? e1 : act;
    c = fmaf(fv, c, iv * gv);
    float hn = ov * tanh_f(c);
    const int nxt = cur ^ 1;
    if (kh == 0) {
      hs[nxt][j] = hn;
      outz[(size_t)pos * H_ + j] = hn;
    }
    asm volatile("s_waitcnt lgkmcnt(0)" ::: "memory");
    __builtin_amdgcn_s_barrier();
    cur = nxt; xv = xvn;
  }
}

// ---------------- attention + pairwise rows. grid (16, 2, 4) block 256.
__global__ __launch_bounds__(256) void k_att(
    fp __restrict__ con, fp w3, fp w4,
    float* __restrict__ att, float* __restrict__ ameanh, float* __restrict__ amaxh,
    float* __restrict__ pcpart, float* __restrict__ mv)
{
  const int b = blockIdx.x, dir = blockIdx.y, lt = blockIdx.z;
  const int l0 = lt * 32;
  fp __restrict__ cp = con + ((size_t)dir * B_ + b) * L_ * H_;
  fp __restrict__ ch = con + ((size_t)(2 + dir) * B_ + b) * L_ * H_;
  fp w = dir ? w4 : w3;
  float* __restrict__ attg = att + ((size_t)dir * B_ + b) * L_ * L_;
  __shared__ float cps[32][132];
  __shared__ float chs[32][132];
  __shared__ float w2s[4][128];
  __shared__ float attb[32][33];
  __shared__ float pcb[4][32][33];
  __shared__ float n0l[32], nql[4][32], n0m[32], nqm[4][32], asum_s[32];
  const int tid = threadIdx.x;
  for (int i = tid; i < 512; i += 256) {
    float wv = w[i];
    w2s[i >> 7][i & 127] = wv * wv;
  }
  for (int i = tid; i < 4096; i += 256)
    cps[i >> 7][i & 127] = cp[(size_t)(l0 + (i >> 7)) * H_ + (i & 127)];
  __syncthreads();
  for (int d = tid; d < 160; d += 256) {
    int l = d / 5, q = d - l * 5;
    const float4* vr = (const float4*)&cps[l][0];
    float s = 0.f;
    if (q == 0) {
      #pragma unroll 8
      for (int h4 = 0; h4 < 32; ++h4) {
        float4 v = vr[h4];
        s += v.x*v.x + v.y*v.y + v.z*v.z + v.w*v.w;
      }
      n0l[l] = sqrtf(s);
    } else {
      const float4* wr = (const float4*)&w2s[q - 1][0];
      #pragma unroll 8
      for (int h4 = 0; h4 < 32; ++h4) {
        float4 v = vr[h4]; float4 ww = wr[h4];
        s += v.x*v.x*ww.x + v.y*v.y*ww.y + v.z*v.z*ww.z + v.w*v.w*ww.w;
      }
      nql[q - 1][l] = sqrtf(s);
    }
  }
  const int tl = tid >> 3, t8 = tid & 7;
  float amean_acc[16], amax_acc[16];
  #pragma unroll
  for (int i = 0; i < 16; ++i) { amean_acc[i] = 0.f; amax_acc[i] = -3.4e38f; }
  float asum_reg = 0.f;
  float pmax_reg = -3.4e38f;
  for (int mc = 0; mc < 4; ++mc) {
    __syncthreads();
    for (int i = tid; i < 4096; i += 256)
      chs[i >> 7][i & 127] = ch[(size_t)(mc * 32 + (i >> 7)) * H_ + (i & 127)];
    __syncthreads();
    for (int d = tid; d < 160; d += 256) {
      int m = d / 5, q = d - m * 5;
      const float4* vr = (const float4*)&chs[m][0];
      float s = 0.f;
      if (q == 0) {
        #pragma unroll 8
        for (int h4 = 0; h4 < 32; ++h4) {
          float4 v = vr[h4];
          s += v.x*v.x + v.y*v.y + v.z*v.z + v.w*v.w;
        }
        n0m[m] = sqrtf(s);
      } else {
        const float4* wr = (const float4*)&w2s[q - 1][0];
        #pragma unroll 8
        for (int h4 = 0; h4 < 32; ++h4) {
          float4 v = vr[h4]; float4 ww = wr[h4];
          s += v.x*v.x*ww.x + v.y*v.y*ww.y + v.z*v.z*ww.z + v.w*v.w*ww.w;
        }
        nqm[q - 1][m] = sqrtf(s);
      }
    }
    __syncthreads();
    // phase A: gram rows for {1, w0..w3} weightings
    float a0[4], ap0[4], ap1[4], ap2[4], ap3[4];
    #pragma unroll
    for (int mm = 0; mm < 4; ++mm) { a0[mm]=0.f; ap0[mm]=0.f; ap1[mm]=0.f; ap2[mm]=0.f; ap3[mm]=0.f; }
    #pragma unroll 4
    for (int h4 = 0; h4 < 32; ++h4) {
      const float4 av = *(const float4*)&cps[tl][h4 * 4];
      const float4 q0 = *(const float4*)&w2s[0][h4 * 4];
      const float4 q1 = *(const float4*)&w2s[1][h4 * 4];
      const float4 q2 = *(const float4*)&w2s[2][h4 * 4];
      const float4 q3 = *(const float4*)&w2s[3][h4 * 4];
      #pragma unroll
      for (int mm = 0; mm < 4; ++mm) {
        const float4 cv = *(const float4*)&chs[t8 * 4 + mm][h4 * 4];
        float px = av.x * cv.x, py = av.y * cv.y, pz = av.z * cv.z, pw = av.w * cv.w;
        a0[mm] += (px + py) + (pz + pw);
        ap0[mm] += px * q0.x + py * q0.y + pz * q0.z + pw * q0.w;
        ap1[mm] += px * q1.x + py * q1.y + pz * q1.z + pw * q1.w;
        ap2[mm] += px * q2.x + py * q2.y + pz * q2.z + pw * q2.w;
        ap3[mm] += px * q3.x + py * q3.y + pz * q3.z + pw * q3.w;
      }
    }
    #pragma unroll
    for (int mm = 0; mm < 4; ++mm) {
      const int m = t8 * 4 + mm;
      float attv = ddiv(a0[mm], n0l[tl] * n0m[m]);
      attb[tl][m] = attv;
      attg[(size_t)(l0 + tl) * L_ + mc * 32 + m] = attv;
      pcb[0][tl][m] = ddiv(ap0[mm], nql[0][tl] * nqm[0][m]);
      pcb[1][tl][m] = ddiv(ap1[mm], nql[1][tl] * nqm[1][m]);
      pcb[2][tl][m] = ddiv(ap2[mm], nql[2][tl] * nqm[2][m]);
      pcb[3][tl][m] = ddiv(ap3[mm], nql[3][tl] * nqm[3][m]);
    }
    __syncthreads();
    // phase B: row reductions over this m-chunk
    for (int mq = 0; mq < 32; ++mq) {
      float avv = attb[tl][mq];
      const float4* cr = (const float4*)&chs[mq][t8 * 16];
      #pragma unroll
      for (int i = 0; i < 4; ++i) {
        float4 cv = cr[i];
        float t0 = avv * cv.x, t1 = avv * cv.y, t2 = avv * cv.z, t3 = avv * cv.w;
        amean_acc[4*i+0] += t0; amax_acc[4*i+0] = fmaxf(amax_acc[4*i+0], t0);
        amean_acc[4*i+1] += t1; amax_acc[4*i+1] = fmaxf(amax_acc[4*i+1], t1);
        amean_acc[4*i+2] += t2; amax_acc[4*i+2] = fmaxf(amax_acc[4*i+2], t2);
        amean_acc[4*i+3] += t3; amax_acc[4*i+3] = fmaxf(amax_acc[4*i+3], t3);
      }
    }
    if (tid < 32) {
      float s = 0.f;
      for (int mq = 0; mq < 32; ++mq) s += attb[tid][mq];
      asum_reg += s;
    }
    if (tid < 128) {
      const int p = tid >> 5, q = tid & 31;
      float mx = pmax_reg;
      for (int mq = 0; mq < 32; ++mq) mx = fmaxf(mx, pcb[p][q][mq]);
      pmax_reg = mx;
      float mx2 = -3.4e38f;
      for (int lq = 0; lq < 32; ++lq) mx2 = fmaxf(mx2, pcb[p][lq][q]);
      pcpart[((((size_t)dir * B_ + b) * 4 + lt) * 4 + p) * L_ + mc * 32 + q] = mx2;
    }
    __syncthreads();
  }
  if (tid < 32) asum_s[tid] = asum_reg;
  __syncthreads();
  {
    float den = asum_s[tl]; den = (den > EPSV) ? den : EPSV;
    const size_t base = (((size_t)dir * B_ + b) * L_ + l0 + tl) * H_ + t8 * 16;
    #pragma unroll
    for (int i = 0; i < 16; ++i) {
      ameanh[base + i] = amean_acc[i] / den;
      amaxh[base + i] = amax_acc[i];
    }
  }
  if (tid < 128) {
    const int p = tid >> 5, lq = tid & 31;
    mv[(size_t)(b * L_ + l0 + lq) * 32 + (dir ? 20 : 4) + p] = pmax_reg;
  }
}

// ---------------- column reductions. grid (16, 2, 4) block 256.
__global__ __launch_bounds__(256) void k_col(
    fp __restrict__ con, fp __restrict__ att,
    fp __restrict__ pcpart,
    float* __restrict__ ameanp, float* __restrict__ amaxp, float* __restrict__ mv)
{
  const int b = blockIdx.x, dir = blockIdx.y, mt = blockIdx.z;
  const int m0 = mt * 32;
  fp __restrict__ cp = con + ((size_t)dir * B_ + b) * L_ * H_;
  fp __restrict__ attg = att + ((size_t)dir * B_ + b) * L_ * L_;
  __shared__ float atts[128][33];
  __shared__ float cpc[32][132];
  __shared__ float asum_s[32];
  const int tid = threadIdx.x;
  for (int i = tid; i < 4096; i += 256)
    atts[i >> 5][i & 31] = attg[(size_t)(i >> 5) * L_ + m0 + (i & 31)];
  __syncthreads();
  if (tid < 32) {
    float s = 0.f;
    for (int l = 0; l < 128; ++l) s += atts[l][tid];
    asum_s[tid] = s;
  }
  const int tm = tid >> 3, t8 = tid & 7;
  float mean_acc[16], max_acc[16];
  #pragma unroll
  for (int i = 0; i < 16; ++i) { mean_acc[i] = 0.f; max_acc[i] = -3.4e38f; }
  for (int lc = 0; lc < 4; ++lc) {
    __syncthreads();
    for (int i = tid; i < 4096; i += 256)
      cpc[i >> 7][i & 127] = cp[(size_t)(lc * 32 + (i >> 7)) * H_ + (i & 127)];
    __syncthreads();
    for (int lq = 0; lq < 32; ++lq) {
      float avv = atts[lc * 32 + lq][tm];
      const float4* cr = (const float4*)&cpc[lq][t8 * 16];
      #pragma unroll
      for (int i = 0; i < 4; ++i) {
        float4 cv = cr[i];
        float t0 = avv * cv.x, t1 = avv * cv.y, t2 = avv * cv.z, t3 = avv * cv.w;
        mean_acc[4*i+0] += t0; max_acc[4*i+0] = fmaxf(max_acc[4*i+0], t0);
        mean_acc[4*i+1] += t1; max_acc[4*i+1] = fmaxf(max_acc[4*i+1], t1);
        mean_acc[4*i+2] += t2; max_acc[4*i+2] = fmaxf(max_acc[4*i+2], t2);
        mean_acc[4*i+3] += t3; max_acc[4*i+3] = fmaxf(max_acc[4*i+3], t3);
      }
    }
  }
  __syncthreads();
  {
    float den = asum_s[tm]; den = (den > EPSV) ? den : EPSV;
    const size_t base = (((size_t)dir * B_ + b) * L_ + m0 + tm) * H_ + t8 * 16;
    #pragma unroll
    for (int i = 0; i < 16; ++i) {
      ameanp[base + i] = mean_acc[i] / den;
      amaxp[base + i] = max_acc[i];
    }
  }
  if (tid < 128) {
    const int p = tid >> 5, mq = tid & 31;
    float mx = -3.4e38f;
    #pragma unroll
    for (int lt = 0; lt < 4; ++lt)
      mx = fmaxf(mx, pcpart[((((size_t)dir * B_ + b) * 4 + lt) * 4 + p) * L_ + m0 + mq]);
    mv[(size_t)(ML_ + b * L_ + m0 + mq) * 32 + (dir ? 20 : 4) + p] = mx;
  }
}

// ---------------- full / att-mean / att-max cosine perspectives. 98304 threads.
__global__ __launch_bounds__(256) void k_mv(
    fp __restrict__ con,
    fp __restrict__ ameanh, fp __restrict__ amaxh,
    fp __restrict__ ameanp, fp __restrict__ amaxp,
    fp w1, fp w2, fp w5, fp w6, fp w7, fp w8,
    float* __restrict__ mv)
{
  int idx = blockIdx.x * 256 + threadIdx.x;
  const int p = idx & 3; int t1 = idx >> 2;
  const int type = t1 % 3; int t2 = t1 / 3;
  const int dir = t2 & 1; int t3 = t2 >> 1;
  const int l = t3 & 127; int t4 = t3 >> 7;
  const int b = t4 & 15; const int side = t4 >> 4;
  const float* v1 = con + (((size_t)(side ? 2 : 0) + dir) * B_ + b) * L_ * H_ + (size_t)l * H_;
  const float* v2;
  if (type == 0) {
    v2 = con + (((size_t)(side ? 0 : 2) + dir) * B_ + b) * L_ * H_ + (size_t)(dir ? 0 : L_ - 1) * H_;
  } else {
    const float* base = (type == 1) ? (side ? ameanp : ameanh) : (side ? amaxp : amaxh);
    v2 = base + (((size_t)dir * B_ + b) * L_ + l) * H_;
  }
  fp w = (type == 0) ? (dir ? w2 : w1) : (type == 1) ? (dir ? w6 : w5) : (dir ? w8 : w7);
  w += p * H_;
  float num = 0.f, s1 = 0.f, s2 = 0.f;
  for (int h = 0; h < H_; ++h) {
    float wv = w[h];
    float a = v1[h] * wv, bb = v2[h] * wv;
    num = fmaf(a, bb, num);
    s1 = fmaf(a, a, s1);
    s2 = fmaf(bb, bb, s2);
  }
  float den = sqrtf(s1) * sqrtf(s2);
  int slot = (type == 0) ? (dir ? 16 : 0) + p : (type == 1) ? (dir ? 24 : 8) + p : (dir ? 28 : 12) + p;
  mv[((size_t)side * ML_ + b * L_ + l) * 32 + slot] = ddiv(num, den);
}

// ---------------- aggregation input projection (K=32). grid (256, 4) block 256.
__global__ __launch_bounds__(256) void k_aggproj(
    fp __restrict__ mv,
    fp Wf, fp Wb, fp bihf, fp bhhf, fp bihb, fp bhhb,
    float* __restrict__ xg)
{
  const int z = blockIdx.y, side = z >> 1, dir = z & 1;
  fp W = dir ? Wb : Wf;
  fp bih = dir ? bihb : bihf;
  fp bhh = dir ? bhhb : bhhf;
  const int r0 = blockIdx.x * 8;
  const float* src = mv + ((size_t)side * ML_ + r0) * 32;
  float* out = xg + ((size_t)z * ML_ + r0) * G_;
  __shared__ float mvs[8][32];
  const int tid = threadIdx.x;
  mvs[tid >> 5][tid & 31] = src[tid];
  __syncthreads();
  float w0[32], w1v[32];
  {
    const float4* wp = (const float4*)(W + (size_t)tid * 32);
    #pragma unroll
    for (int q = 0; q < 8; ++q) {
      float4 u = wp[q];
      w0[4*q+0] = u.x; w0[4*q+1] = u.y; w0[4*q+2] = u.z; w0[4*q+3] = u.w;
    }
    const float4* wp2 = (const float4*)(W + (size_t)(tid + 256) * 32);
    #pragma unroll
    for (int q = 0; q < 8; ++q) {
      float4 u = wp2[q];
      w1v[4*q+0] = u.x; w1v[4*q+1] = u.y; w1v[4*q+2] = u.z; w1v[4*q+3] = u.w;
    }
  }
  float bias0 = bih[tid] + bhh[tid];
  float bias1 = bih[tid + 256] + bhh[tid + 256];
  for (int r = 0; r < 8; ++r) {
    float acc0 = bias0, acc1 = bias1;
    #pragma unroll
    for (int k = 0; k < 32; ++k) {
      float xv = mvs[r][k];
      acc0 = fmaf(w0[k], xv, acc0);
      acc1 = fmaf(w1v[k], xv, acc1);
    }
    out[(size_t)r * G_ + tid] = acc0;
    out[(size_t)r * G_ + tid + 256] = acc1;
  }
}

// ---------------- FC head. grid 16 block 256.
__global__ __launch_bounds__(256) void k_fc(
    fp __restrict__ aggseq,
    fp fc1W, fp fc1b, fp fc2W, fp fc2b,
    float* __restrict__ out)
{
  const int b = blockIdx.x, tid = threadIdx.x;
  __shared__ float x[512];
  __shared__ float y[256];
  for (int i = tid; i < 512; i += 256) {
    int z = i >> 7, h = i & 127;
    int l = (z & 1) ? 0 : (L_ - 1);
    x[i] = aggseq[(((size_t)z * B_ + b) * L_ + l) * H_ + h];
  }
  __syncthreads();
  {
    float acc = fc1b[tid];
    const float4* wr = (const float4*)(fc1W + (size_t)tid * 512);
    const float4* x4 = (const float4*)x;
    #pragma unroll 8
    for (int k4 = 0; k4 < 128; ++k4) {
      float4 u = wr[k4];
      float4 xv = x4[k4];
      acc = fmaf(u.x, xv.x, acc);
      acc = fmaf(u.y, xv.y, acc);
      acc = fmaf(u.z, xv.z, acc);
      acc = fmaf(u.w, xv.w, acc);
    }
    y[tid] = tanh_f(acc);
  }
  __syncthreads();
  if (tid < 2) {
    float acc = fc2b[tid];
    for (int k = 0; k < 256; ++k) acc = fmaf(fc2W[tid * 256 + k], y[k], acc);
    out[b * 2 + tid] = acc;
  }
}

extern "C" void kernel_launch(void* const* d_in, const int* in_sizes, int n_in,
                              void* d_out, int out_size, void* d_ws, size_t ws_size,
                              hipStream_t stream) {
  (void)in_sizes; (void)n_in; (void)out_size; (void)ws_size;
  const int* ta = (const int*)d_in[0];
  const int* tb = (const int*)d_in[1];
  fp emb   = (fp)d_in[2];
  fp cWihf = (fp)d_in[3];
  fp cWhhf = (fp)d_in[4];
  fp cbihf = (fp)d_in[5];
  fp cbhhf = (fp)d_in[6];
  fp cWihb = (fp)d_in[7];
  fp cWhhb = (fp)d_in[8];
  fp cbihb = (fp)d_in[9];
  fp cbhhb = (fp)d_in[10];
  fp aWihf = (fp)d_in[11];
  fp aWhhf = (fp)d_in[12];
  fp abihf = (fp)d_in[13];
  fp abhhf = (fp)d_in[14];
  fp aWihb = (fp)d_in[15];
  fp aWhhb = (fp)d_in[16];
  fp abihb = (fp)d_in[17];
  fp abhhb = (fp)d_in[18];
  fp fc1W  = (fp)d_in[19];
  fp fc1b  = (fp)d_in[20];
  fp fc2W  = (fp)d_in[21];
  fp fc2b  = (fp)d_in[22];
  fp w1 = (fp)d_in[23];
  fp w2 = (fp)d_in[24];
  fp w3 = (fp)d_in[25];
  fp w4 = (fp)d_in[26];
  fp w5 = (fp)d_in[27];
  fp w6 = (fp)d_in[28];
  fp w7 = (fp)d_in[29];
  fp w8 = (fp)d_in[30];

  float* ws = (float*)d_ws;
  float* xg     = ws;                                   // 4*ML*G (reused for agg)
  float* con    = xg     + (size_t)4 * ML_ * G_;        // 4*ML*H
  float* attw   = con    + (size_t)4 * ML_ * H_;        // 2*B*L*L
  float* ameanh = attw   + (size_t)2 * B_ * L_ * L_;    // 2*ML*H
  float* amaxh  = ameanh + (size_t)2 * ML_ * H_;
  float* ameanp = amaxh  + (size_t)2 * ML_ * H_;
  float* amaxp  = ameanp + (size_t)2 * ML_ * H_;
  float* pcpart = amaxp  + (size_t)2 * ML_ * H_;        // 2*B*16*L
  float* mvb    = pcpart + (size_t)2 * B_ * 16 * L_;    // 2*ML*32
  float* aggseq = mvb    + (size_t)2 * ML_ * 32;        // 4*ML*H

  k_proj<<<dim3(32, 8, 4), 256, 0, stream>>>(emb, ta, tb, cWihf, cWihb,
                                             cbihf, cbhhf, cbihb, cbhhb, xg);
  k_lstm<<<dim3(16, 4), 512, 0, stream>>>(xg, cWhhf, cWhhb, con);
  k_att<<<dim3(16, 2, 4), 256, 0, stream>>>(con, w3, w4, attw, ameanh, amaxh, pcpart, mvb);
  k_col<<<dim3(16, 2, 4), 256, 0, stream>>>(con, attw, pcpart, ameanp, amaxp, mvb);
  k_mv<<<384, 256, 0, stream>>>(con, ameanh, amaxh, ameanp, amaxp, w1, w2, w5, w6, w7, w8, mvb);
  k_aggproj<<<dim3(256, 4), 256, 0, stream>>>(mvb, aWihf, aWihb, abihf, abhhf, abihb, abhhb, xg);
  k_lstm<<<dim3(16, 4), 512, 0, stream>>>(xg, aWhhf, aWhhb, aggseq);
  k_fc<<<16, 256, 0, stream>>>(aggseq, fc1W, fc1b, fc2W, fc2b, (float*)d_out);
}